// Round 1
// 904.308 us; speedup vs baseline: 1.0237x; 1.0237x over previous
//
#include <hip/hip_runtime.h>

// Problem: B=8, L=1024, H=1024, M=128, V=32 (V^2=1024). All fp32 in/out.
// Strategy: everything cast to fp16 for MFMA; big GEMM fuses pairs-construction
// into the A-fragment via per-K q-row scaling (A = k_frag * q_scale).
//
// big_gemm v2: 256(row=2i x 128j) x 256(v) tile, BK=64, 8 waves, 4-phase
// schedule per K-tile with counted vmcnt(6) (never 0 in loop), 3-slot LDS
// ring (depth-2 prefetch), XOR-swizzled LDS (read side) with inverse-swizzled
// global_load_lds sources (linear LDS dest), setprio around MFMA clusters.
//
// WS layout (MiB offsets): x_h@0(16) q_h@16(2) k_h@18(2) wq_h@20(2) wk_h@22(2)
//                          we_h@24(2) wm_h@26(64KB) span@27(32KB)  => ~27.1 MB

typedef float   f32x4 __attribute__((ext_vector_type(4)));
typedef _Float16 f16x8 __attribute__((ext_vector_type(8)));

__device__ __forceinline__ void gld16(const void* g, void* l) {
  __builtin_amdgcn_global_load_lds(
      (const __attribute__((address_space(1))) void*)g,
      (__attribute__((address_space(3))) void*)l, 16, 0, 0);
}

// ---------------- weight fp32 -> fp16 convert (4 segments) ----------------
__global__ __launch_bounds__(256) void cvt_kernel(
    const float* __restrict__ wq, const float* __restrict__ wk,
    const float* __restrict__ we, const float* __restrict__ wm,
    _Float16* __restrict__ oq, _Float16* __restrict__ ok,
    _Float16* __restrict__ oe, _Float16* __restrict__ om) {
  int id = blockIdx.x * 256 + threadIdx.x;  // float4 units, total 794624
  const float* src; _Float16* dst; int off;
  if (id < 262144)      { src = wq; dst = oq; off = id; }
  else if (id < 524288) { src = wk; dst = ok; off = id - 262144; }
  else if (id < 786432) { src = we; dst = oe; off = id - 524288; }
  else                  { src = wm; dst = om; off = id - 786432; }
  float4 v = ((const float4*)src)[off];
  union { _Float16 h[4]; uint2 u; } o;
  o.h[0] = (_Float16)v.x; o.h[1] = (_Float16)v.y;
  o.h[2] = (_Float16)v.z; o.h[3] = (_Float16)v.w;
  ((uint2*)dst)[off] = o.u;
}

// ---------------- LayerNorm: x_enc (8192 x 1024) -> x_h fp16 ----------------
__global__ __launch_bounds__(256) void ln_kernel(
    const float* __restrict__ x, const float* __restrict__ g,
    const float* __restrict__ be, _Float16* __restrict__ xo) {
  const int row = blockIdx.x, t = threadIdx.x;
  const float4 v = ((const float4*)(x + (size_t)row * 1024))[t];
  float s1 = v.x + v.y + v.z + v.w;
  float s2 = v.x * v.x + v.y * v.y + v.z * v.z + v.w * v.w;
  #pragma unroll
  for (int m = 1; m < 64; m <<= 1) {
    s1 += __shfl_xor(s1, m, 64);
    s2 += __shfl_xor(s2, m, 64);
  }
  __shared__ float red[8];
  const int w = t >> 6, lane = t & 63;
  if (lane == 0) { red[w * 2] = s1; red[w * 2 + 1] = s2; }
  __syncthreads();
  s1 = red[0] + red[2] + red[4] + red[6];
  s2 = red[1] + red[3] + red[5] + red[7];
  const float mu = s1 * (1.f / 1024.f);
  const float var = s2 * (1.f / 1024.f) - mu * mu;
  const float rs = rsqrtf(var + 1e-5f);
  const float4 gv = ((const float4*)g)[t];
  const float4 bv = ((const float4*)be)[t];
  union { _Float16 h[4]; uint2 u; } o;
  o.h[0] = (_Float16)((v.x - mu) * rs * gv.x + bv.x);
  o.h[1] = (_Float16)((v.y - mu) * rs * gv.y + bv.y);
  o.h[2] = (_Float16)((v.z - mu) * rs * gv.z + bv.z);
  o.h[3] = (_Float16)((v.w - mu) * rs * gv.w + bv.w);
  ((uint2*)(xo + (size_t)row * 1024))[t] = o.u;
}

// ------------- q/k GEMM: gathered masked_x (1024x1024) @ W^T, NT -------------
// 64x64 tile, BK=32, 4 waves: wave w owns m-subtile w x 4 n-subtiles.
__global__ __launch_bounds__(256, 4) void qk_gemm(
    const _Float16* __restrict__ xh, const _Float16* __restrict__ wq,
    const _Float16* __restrict__ wk, const int* __restrict__ midx,
    _Float16* __restrict__ qout, _Float16* __restrict__ kout) {
  __shared__ _Float16 at[64 * 32];
  __shared__ _Float16 bt[64 * 32];
  const int tid = threadIdx.x, w = tid >> 6, lane = tid & 63;
  const int l15 = lane & 15, quad = lane >> 4;
  const int ntile = blockIdx.x, rtile = blockIdx.y, mat = blockIdx.z;
  const _Float16* wmat = mat ? wk : wq;
  _Float16* outp = mat ? kout : qout;

  // staging: thread tid stages 16B chunk tid; row=tid/4, col8=(tid%4)*8
  const int arow = tid >> 2;           // 0..63
  const int acol = (tid & 3) * 8;      // fp16 elems
  const int grow = rtile * 64 + arow;  // 0..1023 => (b,m)
  const int b = grow >> 7, m = grow & 127;
  const int src = midx[b * 128 + m];   // gather row in L
  const _Float16* agp = xh + ((size_t)(b * 1024 + src)) * 1024 + acol;
  const _Float16* bgp = wmat + (size_t)(ntile * 64 + arow) * 1024 + acol;
  char* aldst = (char*)at + w * 1024;  // wave-uniform base; HW adds lane*16
  char* bldst = (char*)bt + w * 1024;

  f32x4 acc[4];
  const f32x4 zero = {0.f, 0.f, 0.f, 0.f};
  #pragma unroll
  for (int ns = 0; ns < 4; ++ns) acc[ns] = zero;

  for (int s = 0; s < 32; ++s) {
    const int kk = s * 32;
    gld16(agp + kk, aldst);
    gld16(bgp + kk, bldst);
    __syncthreads();
    const f16x8 af = *(const f16x8*)&at[(w * 16 + l15) * 32 + quad * 8];
    #pragma unroll
    for (int ns = 0; ns < 4; ++ns) {
      const f16x8 bf = *(const f16x8*)&bt[(ns * 16 + l15) * 32 + quad * 8];
      acc[ns] = __builtin_amdgcn_mfma_f32_16x16x32_f16(af, bf, acc[ns], 0, 0, 0);
    }
    __syncthreads();
  }
  #pragma unroll
  for (int ns = 0; ns < 4; ++ns) {
    const int col = ntile * 64 + ns * 16 + l15;
    #pragma unroll
    for (int r = 0; r < 4; ++r) {
      const int row = rtile * 64 + w * 16 + quad * 4 + r;
      outp[(size_t)row * 1024 + col] = (_Float16)acc[ns][r];
    }
  }
}

// ---- big GEMM: logits[(b,i,j), v] = sum_h q[b,i,h]*k[b,j,h]*We[v,h] ----
// Block = (b, i-pair) x 256-wide v-tile. 8 waves: wm = i within pair (2),
// wn = 64-col quarter (4). Per wave: 128 j-rows x 64 v-cols.
// K=1024 as 16 K-tiles of BK=64; per K-tile 4 quadrant phases (mh,nh):
// (0,0)(0,1)(1,1)(1,0) so each A/B fragment set is read once per tile
// (A 16 + B 12 + q 2 ds_read_b128 per wave per tile), 16 MFMA per phase.
// LDS: 3-slot ring of {k-tile 16KB | We-tile 32KB} + q rows 4KB = 148KB.
// Prefetch: tile t+2 staged during tile t's phases -> vmcnt(6) at tile top.
#define BG_BUF 49152
#define BG_WE  16384
#define BG_Q   147456
__global__ __launch_bounds__(512, 2) void big_gemm(
    const _Float16* __restrict__ qf, const _Float16* __restrict__ kf,
    const _Float16* __restrict__ wemb, float* __restrict__ out) {
  __shared__ __align__(16) char lds[151552];
  const int tid = threadIdx.x;
  const int w = tid >> 6, lane = tid & 63;
  const int l15 = lane & 15, quad = lane >> 4;
  const int wm = w >> 2, wn = w & 3;
  const int rtile = blockIdx.x;        // 0..511
  const int vtile = blockIdx.y;        // 0..3
  const int b = rtile >> 6;
  const int i0 = (rtile & 63) * 2;

  // ---- staging: lane l covers LDS 16B slot l of a 1KB wave-chunk.
  // LDS linear (row = base + l>>3, colgroup = l&7); swizzle rule is
  // lds(row, cg) = global(row, cg ^ (row&7)) => source cg' = (l&7)^(l>>3).
  const int lrow = lane >> 3;
  const int cgsw = (lane & 7) ^ lrow;
  const char* kg = (const char*)(kf + (size_t)b * 128 * 1024);
  const char* wg = (const char*)(wemb + (size_t)vtile * 256 * 1024);
  const char* ks0 = kg + (size_t)(((w)      * 8 + lrow) * 2048 + cgsw * 16);
  const char* ks1 = kg + (size_t)(((w + 8)  * 8 + lrow) * 2048 + cgsw * 16);
  const char* ws0 = wg + (size_t)(((w)      * 8 + lrow) * 2048 + cgsw * 16);
  const char* ws1 = wg + (size_t)(((w + 8)  * 8 + lrow) * 2048 + cgsw * 16);
  const char* ws2 = wg + (size_t)(((w + 16) * 8 + lrow) * 2048 + cgsw * 16);
  const char* ws3 = wg + (size_t)(((w + 24) * 8 + lrow) * 2048 + cgsw * 16);
  const int kd0 = w * 1024,          kd1 = (w + 8) * 1024;
  const int wd0 = BG_WE + w * 1024,  wd1 = BG_WE + (w + 8) * 1024;
  const int wd2 = BG_WE + (w + 16) * 1024, wd3 = BG_WE + (w + 24) * 1024;

  // ---- LDS read offsets: row-part + swizzled column part.
  // col bytes in [0,128): (kkh*64 + quad*16) ^ ((row&7)<<4); row&7 == l15&7.
  const int swzb = (l15 & 7) << 4;
  const int col0 = (quad * 16) ^ swzb;
  const int col1 = (64 + quad * 16) ^ swzb;
  const int abase = l15 * 128;                       // + mh*8192 + ms*2048
  const int bbase = BG_WE + (wn * 64 + l15) * 128;   // + nh*4096 + ns*2048
  const int qbase = BG_Q + wm * 2048 + quad * 16;    // + t*128 + kkh*64

  // ---- prologue: q rows (oldest loads), then tiles 0 and 1 ----
  if (w < 4) {
    const char* qsrc = (const char*)(qf + (size_t)(b * 128 + i0 + (w >> 1)) * 1024)
                       + (w & 1) * 1024 + lane * 16;
    gld16(qsrc, lds + BG_Q + w * 1024);
  }
  gld16(ks0, lds + kd0);              gld16(ks1, lds + kd1);
  gld16(ws0, lds + wd0);              gld16(ws1, lds + wd1);
  gld16(ws2, lds + wd2);              gld16(ws3, lds + wd3);
  gld16(ks0 + 128, lds + BG_BUF + kd0); gld16(ks1 + 128, lds + BG_BUF + kd1);
  gld16(ws0 + 128, lds + BG_BUF + wd0); gld16(ws1 + 128, lds + BG_BUF + wd1);
  gld16(ws2 + 128, lds + BG_BUF + wd2); gld16(ws3 + 128, lds + BG_BUF + wd3);

  f32x4 acc[8][4];
  #pragma unroll
  for (int a = 0; a < 8; ++a)
    #pragma unroll
    for (int c = 0; c < 4; ++c) acc[a][c] = (f32x4){0.f, 0.f, 0.f, 0.f};

  f16x8 af[4][2], bf0[2][2], bf1[2][2], qs0, qs1;

#define RD_A(mh)                                                               \
  _Pragma("unroll")                                                            \
  for (int ms = 0; ms < 4; ++ms) {                                             \
    af[ms][0] = *(const f16x8*)(lds + cb + abase + (mh) * 8192 + ms * 2048 + col0); \
    af[ms][1] = *(const f16x8*)(lds + cb + abase + (mh) * 8192 + ms * 2048 + col1); \
  }
#define RD_B(dst, nh)                                                          \
  _Pragma("unroll")                                                            \
  for (int ns = 0; ns < 2; ++ns) {                                             \
    dst[ns][0] = *(const f16x8*)(lds + cb + bbase + (nh) * 4096 + ns * 2048 + col0); \
    dst[ns][1] = *(const f16x8*)(lds + cb + bbase + (nh) * 4096 + ns * 2048 + col1); \
  }
#define MULT_A()                                                               \
  _Pragma("unroll")                                                            \
  for (int ms = 0; ms < 4; ++ms) { af[ms][0] *= qs0; af[ms][1] *= qs1; }
#define MFMA8(MH, NH, BFR)                                                     \
  __builtin_amdgcn_s_setprio(1);                                               \
  _Pragma("unroll")                                                            \
  for (int kh = 0; kh < 2; ++kh)                                               \
    _Pragma("unroll")                                                          \
    for (int ms = 0; ms < 4; ++ms)                                             \
      _Pragma("unroll")                                                        \
      for (int ns = 0; ns < 2; ++ns)                                           \
        acc[(MH) * 4 + ms][(NH) * 2 + ns] = __builtin_amdgcn_mfma_f32_16x16x32_f16( \
            af[ms][kh], BFR[ns][kh], acc[(MH) * 4 + ms][(NH) * 2 + ns], 0, 0, 0);   \
  __builtin_amdgcn_s_setprio(0);
#define BAR() __builtin_amdgcn_s_barrier()
#define LGKM0() asm volatile("s_waitcnt lgkmcnt(0)" ::: "memory")

  int cur = 0;
  #pragma unroll 1
  for (int t = 0; t < 16; ++t) {
    const int cb = cur * BG_BUF;
    int stg = cur + 2; if (stg >= 3) stg -= 3;
    const int sb = stg * BG_BUF;
    const int skb = (t + 2) * 128;      // global col-byte base of tile t+2
    const bool st = (t < 14);

    // tile t resident after this (t+1's 6 loads stay in flight)
    if (t < 15) asm volatile("s_waitcnt vmcnt(6)" ::: "memory");
    else        asm volatile("s_waitcnt vmcnt(0)" ::: "memory");
    BAR();

    // ---- phase 0: (mh0, nh0) ----
    qs0 = *(const f16x8*)(lds + qbase + t * 128);
    qs1 = *(const f16x8*)(lds + qbase + t * 128 + 64);
    RD_A(0)
    RD_B(bf0, 0)
    if (st) { gld16(ks0 + skb, lds + sb + kd0); gld16(ks1 + skb, lds + sb + kd1); }
    BAR(); LGKM0();
    MULT_A()
    MFMA8(0, 0, bf0)
    BAR();
    // ---- phase 1: (mh0, nh1) ----
    RD_B(bf1, 1)
    if (st) { gld16(ws0 + skb, lds + sb + wd0); gld16(ws1 + skb, lds + sb + wd1); }
    BAR(); LGKM0();
    MFMA8(0, 1, bf1)
    BAR();
    // ---- phase 2: (mh1, nh1) — reuse bf1 ----
    RD_A(1)
    if (st) { gld16(ws2 + skb, lds + sb + wd2); gld16(ws3 + skb, lds + sb + wd3); }
    BAR(); LGKM0();
    MULT_A()
    MFMA8(1, 1, bf1)
    BAR();
    // ---- phase 3: (mh1, nh0) — reuse bf0 ----
    BAR(); LGKM0();
    MFMA8(1, 0, bf0)
    BAR();

    cur = cur + 1; if (cur == 3) cur = 0;
  }

  // ---- epilogue: C[j, v] ----
  const size_t nb = (size_t)((b * 128 + i0 + wm)) * 128;
  const int colb = vtile * 256 + wn * 64;
  #pragma unroll
  for (int ms = 0; ms < 8; ++ms) {
    #pragma unroll
    for (int ns = 0; ns < 4; ++ns) {
      #pragma unroll
      for (int r = 0; r < 4; ++r)
        out[(nb + ms * 16 + quad * 4 + r) * 1024 + colb + ns * 16 + l15] =
            acc[ms][ns][r];
    }
  }
#undef RD_A
#undef RD_B
#undef MULT_A
#undef MFMA8
#undef BAR
#undef LGKM0
}

// ------------- mlm_logits: x_h (8192x1024) @ W_mlm^T (32x1024) -------------
// one wave per row; lane: v = lane&31, half-row part = lane>>5.
__global__ __launch_bounds__(256) void mlm_kernel(
    const _Float16* __restrict__ xh, const _Float16* __restrict__ wm,
    float* __restrict__ out) {
  const int w = threadIdx.x >> 6, lane = threadIdx.x & 63;
  const int row = blockIdx.x * 4 + w;
  const int v = lane & 31, part = lane >> 5;
  const f16x8* xr = (const f16x8*)(xh + (size_t)row * 1024 + part * 512);
  const f16x8* wr = (const f16x8*)(wm + (size_t)v * 1024 + part * 512);
  float acc = 0.f;
  #pragma unroll 8
  for (int it = 0; it < 64; ++it) {
    const f16x8 p = xr[it] * wr[it];
    #pragma unroll
    for (int e = 0; e < 8; ++e) acc += (float)p[e];
  }
  acc += __shfl_xor(acc, 32, 64);
  if (part == 0) out[(size_t)row * 32 + v] = acc;
}

// ------- span masks: in_span, mask_aa (out), diag_mask (out), ws copy -------
__global__ __launch_bounds__(256) void span_kernel(
    const int* __restrict__ midx, float* __restrict__ mask_aa,
    float* __restrict__ diag, float* __restrict__ span_ws) {
  __shared__ float flag[1024];
  const int b = blockIdx.x, t = threadIdx.x;
  for (int p = t; p < 1024; p += 256) flag[p] = 0.f;
  __syncthreads();
  if (t < 128) flag[midx[b * 128 + t]] = 1.f;
  __syncthreads();
  for (int p = t; p < 1024; p += 256) {
    const float f = flag[p];
    mask_aa[b * 1024 + p] = f;
    span_ws[b * 1024 + p] = f;
  }
  for (int p = t; p < 16384; p += 256)
    diag[b * 16384 + p] = ((p >> 7) == (p & 127)) ? 1.f : 0.f;
}

// ---------------- pair_mask_aa[b,i,j] = s[b,i]*s[b,j] (8.4M f32) ----------------
__global__ __launch_bounds__(256) void pairmask_kernel(
    const float* __restrict__ span_ws, float* __restrict__ out) {
  const int id = blockIdx.x * 256 + threadIdx.x;  // float4 units, 2M total
  const int b = id >> 18;
  const int rem = id & 262143;
  const int i = rem >> 8;
  const int j4 = rem & 255;
  const float si = span_ws[b * 1024 + i];
  const float4 sj = ((const float4*)(span_ws + b * 1024))[j4];
  float4 o;
  o.x = si * sj.x; o.y = si * sj.y; o.z = si * sj.z; o.w = si * sj.w;
  ((float4*)out)[id] = o;
}

extern "C" void kernel_launch(void* const* d_in, const int* in_sizes, int n_in,
                              void* d_out, int out_size, void* d_ws, size_t ws_size,
                              hipStream_t stream) {
  const float* x_enc = (const float*)d_in[0];
  const float* gam   = (const float*)d_in[1];
  const float* bet   = (const float*)d_in[2];
  const float* Wq    = (const float*)d_in[3];
  const float* Wk    = (const float*)d_in[4];
  const float* We    = (const float*)d_in[5];
  const float* Wm    = (const float*)d_in[6];
  const int*   midx  = (const int*)d_in[7];
  float* out = (float*)d_out;

  char* ws = (char*)d_ws;
  _Float16* x_h  = (_Float16*)(ws);
  _Float16* q_h  = (_Float16*)(ws + ((size_t)16 << 20));
  _Float16* k_h  = (_Float16*)(ws + ((size_t)18 << 20));
  _Float16* wq_h = (_Float16*)(ws + ((size_t)20 << 20));
  _Float16* wk_h = (_Float16*)(ws + ((size_t)22 << 20));
  _Float16* we_h = (_Float16*)(ws + ((size_t)24 << 20));
  _Float16* wm_h = (_Float16*)(ws + ((size_t)26 << 20));
  float* span_ws = (float*)(ws + ((size_t)27 << 20));

  float* o_logits = out;                        // 131072 x 1024
  float* o_mlm    = out + (size_t)134217728;    // 8192 x 32
  float* o_diag   = o_mlm + 262144;             // 131072
  float* o_maskaa = o_diag + 131072;            // 8192
  float* o_pair   = o_maskaa + 8192;            // 8388608

  cvt_kernel<<<3104, 256, 0, stream>>>(Wq, Wk, We, Wm, wq_h, wk_h, we_h, wm_h);
  ln_kernel<<<8192, 256, 0, stream>>>(x_enc, gam, bet, x_h);
  qk_gemm<<<dim3(16, 16, 2), 256, 0, stream>>>(x_h, wq_h, wk_h, midx, q_h, k_h);
  big_gemm<<<dim3(512, 4), 512, 0, stream>>>(q_h, k_h, we_h, o_logits);
  mlm_kernel<<<2048, 256, 0, stream>>>(x_h, wm_h, o_mlm);
  span_kernel<<<8, 256, 0, stream>>>(midx, o_maskaa, o_diag, span_ws);
  pairmask_kernel<<<8192, 256, 0, stream>>>(span_ws, o_pair);
}

// Round 2
// 874.577 us; speedup vs baseline: 1.0585x; 1.0340x over previous
//
#include <hip/hip_runtime.h>

// Problem: B=8, L=1024, H=1024, M=128, V=32 (V^2=1024). All fp32 in/out.
// Strategy: everything cast to fp16 for MFMA; big GEMM fuses pairs-construction
// into the A-fragment via per-K q-row scaling (A = k_frag * q_scale).
//
// big_gemm v3 (persistent): grid = 256 blocks (1/CU), each block owns 8
// consecutive rtiles sharing the SAME b and vtile -> k/We tile stream is
// identical across the 8 iterations (L2-hot), and the 3-slot LDS ring stays
// full ACROSS iterations: per-iter epilogue stores overlap the next iter's
// in-flight prefetch. 256x256 tile, BK=64, 8 waves, 3 phases/K-tile,
// counted vmcnt(6) (never 0 until the final tile), XOR-swizzled LDS reads
// with inverse-swizzled global sources (linear LDS dest), setprio on MFMA.
// q rows ping-pong staged (parity j&1; staged during iter j-1 which reads
// the opposite parity).
//
// WS layout (MiB offsets): x_h@0(16) q_h@16(2) k_h@18(2) wq_h@20(2) wk_h@22(2)
//                          we_h@24(2) wm_h@26(64KB) span@27(32KB)  => ~27.1 MB

typedef float   f32x4 __attribute__((ext_vector_type(4)));
typedef _Float16 f16x8 __attribute__((ext_vector_type(8)));

__device__ __forceinline__ void gld16(const void* g, void* l) {
  __builtin_amdgcn_global_load_lds(
      (const __attribute__((address_space(1))) void*)g,
      (__attribute__((address_space(3))) void*)l, 16, 0, 0);
}

// ---------------- weight fp32 -> fp16 convert (4 segments) ----------------
__global__ __launch_bounds__(256) void cvt_kernel(
    const float* __restrict__ wq, const float* __restrict__ wk,
    const float* __restrict__ we, const float* __restrict__ wm,
    _Float16* __restrict__ oq, _Float16* __restrict__ ok,
    _Float16* __restrict__ oe, _Float16* __restrict__ om) {
  int id = blockIdx.x * 256 + threadIdx.x;  // float4 units, total 794624
  const float* src; _Float16* dst; int off;
  if (id < 262144)      { src = wq; dst = oq; off = id; }
  else if (id < 524288) { src = wk; dst = ok; off = id - 262144; }
  else if (id < 786432) { src = we; dst = oe; off = id - 524288; }
  else                  { src = wm; dst = om; off = id - 786432; }
  float4 v = ((const float4*)src)[off];
  union { _Float16 h[4]; uint2 u; } o;
  o.h[0] = (_Float16)v.x; o.h[1] = (_Float16)v.y;
  o.h[2] = (_Float16)v.z; o.h[3] = (_Float16)v.w;
  ((uint2*)dst)[off] = o.u;
}

// ---------------- LayerNorm: x_enc (8192 x 1024) -> x_h fp16 ----------------
__global__ __launch_bounds__(256) void ln_kernel(
    const float* __restrict__ x, const float* __restrict__ g,
    const float* __restrict__ be, _Float16* __restrict__ xo) {
  const int row = blockIdx.x, t = threadIdx.x;
  const float4 v = ((const float4*)(x + (size_t)row * 1024))[t];
  float s1 = v.x + v.y + v.z + v.w;
  float s2 = v.x * v.x + v.y * v.y + v.z * v.z + v.w * v.w;
  #pragma unroll
  for (int m = 1; m < 64; m <<= 1) {
    s1 += __shfl_xor(s1, m, 64);
    s2 += __shfl_xor(s2, m, 64);
  }
  __shared__ float red[8];
  const int w = t >> 6, lane = t & 63;
  if (lane == 0) { red[w * 2] = s1; red[w * 2 + 1] = s2; }
  __syncthreads();
  s1 = red[0] + red[2] + red[4] + red[6];
  s2 = red[1] + red[3] + red[5] + red[7];
  const float mu = s1 * (1.f / 1024.f);
  const float var = s2 * (1.f / 1024.f) - mu * mu;
  const float rs = rsqrtf(var + 1e-5f);
  const float4 gv = ((const float4*)g)[t];
  const float4 bv = ((const float4*)be)[t];
  union { _Float16 h[4]; uint2 u; } o;
  o.h[0] = (_Float16)((v.x - mu) * rs * gv.x + bv.x);
  o.h[1] = (_Float16)((v.y - mu) * rs * gv.y + bv.y);
  o.h[2] = (_Float16)((v.z - mu) * rs * gv.z + bv.z);
  o.h[3] = (_Float16)((v.w - mu) * rs * gv.w + bv.w);
  ((uint2*)(xo + (size_t)row * 1024))[t] = o.u;
}

// ------------- q/k GEMM: gathered masked_x (1024x1024) @ W^T, NT -------------
// 64x64 tile, BK=32, 4 waves: wave w owns m-subtile w x 4 n-subtiles.
__global__ __launch_bounds__(256, 4) void qk_gemm(
    const _Float16* __restrict__ xh, const _Float16* __restrict__ wq,
    const _Float16* __restrict__ wk, const int* __restrict__ midx,
    _Float16* __restrict__ qout, _Float16* __restrict__ kout) {
  __shared__ _Float16 at[64 * 32];
  __shared__ _Float16 bt[64 * 32];
  const int tid = threadIdx.x, w = tid >> 6, lane = tid & 63;
  const int l15 = lane & 15, quad = lane >> 4;
  const int ntile = blockIdx.x, rtile = blockIdx.y, mat = blockIdx.z;
  const _Float16* wmat = mat ? wk : wq;
  _Float16* outp = mat ? kout : qout;

  // staging: thread tid stages 16B chunk tid; row=tid/4, col8=(tid%4)*8
  const int arow = tid >> 2;           // 0..63
  const int acol = (tid & 3) * 8;      // fp16 elems
  const int grow = rtile * 64 + arow;  // 0..1023 => (b,m)
  const int b = grow >> 7, m = grow & 127;
  const int src = midx[b * 128 + m];   // gather row in L
  const _Float16* agp = xh + ((size_t)(b * 1024 + src)) * 1024 + acol;
  const _Float16* bgp = wmat + (size_t)(ntile * 64 + arow) * 1024 + acol;
  char* aldst = (char*)at + w * 1024;  // wave-uniform base; HW adds lane*16
  char* bldst = (char*)bt + w * 1024;

  f32x4 acc[4];
  const f32x4 zero = {0.f, 0.f, 0.f, 0.f};
  #pragma unroll
  for (int ns = 0; ns < 4; ++ns) acc[ns] = zero;

  for (int s = 0; s < 32; ++s) {
    const int kk = s * 32;
    gld16(agp + kk, aldst);
    gld16(bgp + kk, bldst);
    __syncthreads();
    const f16x8 af = *(const f16x8*)&at[(w * 16 + l15) * 32 + quad * 8];
    #pragma unroll
    for (int ns = 0; ns < 4; ++ns) {
      const f16x8 bf = *(const f16x8*)&bt[(ns * 16 + l15) * 32 + quad * 8];
      acc[ns] = __builtin_amdgcn_mfma_f32_16x16x32_f16(af, bf, acc[ns], 0, 0, 0);
    }
    __syncthreads();
  }
  #pragma unroll
  for (int ns = 0; ns < 4; ++ns) {
    const int col = ntile * 64 + ns * 16 + l15;
    #pragma unroll
    for (int r = 0; r < 4; ++r) {
      const int row = rtile * 64 + w * 16 + quad * 4 + r;
      outp[(size_t)row * 1024 + col] = (_Float16)acc[ns][r];
    }
  }
}

// ---- big GEMM: logits[(b,i,j), v] = sum_h q[b,i,h]*k[b,j,h]*We[v,h] ----
// Persistent: block = (vtile, grp); grp fixes b and an i0-range of 8 i-pairs.
// 8 iterations j: rtile = grp*8+j, i0 = (grp&7)*16 + 2j. k/We sources are
// IDENTICAL across iterations (same b, same vtile) -> L2-hot ring re-stream.
// Global tile counter T=0..127 (8 iters x 16 K-tiles); ring slot = T mod 3;
// tile T+2 staged during T; vmcnt(6) at tile top (vmcnt(0) only at T=127).
#define BG_BUF 49152
#define BG_Q   147456
#define BG_WE  16384
__global__ __launch_bounds__(512, 2) void big_gemm(
    const _Float16* __restrict__ qf, const _Float16* __restrict__ kf,
    const _Float16* __restrict__ wemb, float* __restrict__ out) {
  __shared__ __align__(16) char lds[155648];  // 3*48KB ring + 2*4KB q
  const int tid = threadIdx.x;
  const int w = tid >> 6, lane = tid & 63;
  const int l15 = lane & 15, quad = lane >> 4;
  const int wm = w >> 2, wn = w & 3;
  const int bid = blockIdx.x;          // 0..255
  const int vtile = bid & 3;           // 0..3
  const int grp = bid >> 2;            // 0..63
  const int b = grp >> 3;              // 0..7 (fixed per block)
  const int i0base = (grp & 7) * 16;   // i0 for iter j: i0base + 2j

  // ---- staging: lane l covers LDS 16B slot l of a 1KB wave-chunk.
  // LDS linear (row = base + l>>3, colgroup = l&7); swizzle rule is
  // lds(row, cg) = global(row, cg ^ (row&7)) => source cg' = (l&7)^(l>>3).
  const int lrow = lane >> 3;
  const int cgsw = (lane & 7) ^ lrow;
  const char* kg = (const char*)(kf + (size_t)b * 128 * 1024);
  const char* wg = (const char*)(wemb + (size_t)vtile * 256 * 1024);
  const char* ks0 = kg + (size_t)(((w)      * 8 + lrow) * 2048 + cgsw * 16);
  const char* ks1 = kg + (size_t)(((w + 8)  * 8 + lrow) * 2048 + cgsw * 16);
  const char* ws0 = wg + (size_t)(((w)      * 8 + lrow) * 2048 + cgsw * 16);
  const char* ws1 = wg + (size_t)(((w + 8)  * 8 + lrow) * 2048 + cgsw * 16);
  const char* ws2 = wg + (size_t)(((w + 16) * 8 + lrow) * 2048 + cgsw * 16);
  const char* ws3 = wg + (size_t)(((w + 24) * 8 + lrow) * 2048 + cgsw * 16);
  const int kd0 = w * 1024,          kd1 = (w + 8) * 1024;
  const int wd0 = BG_WE + w * 1024,  wd1 = BG_WE + (w + 8) * 1024;
  const int wd2 = BG_WE + (w + 16) * 1024, wd3 = BG_WE + (w + 24) * 1024;

  // q staging: waves 0..3 each stage 1KB; dest = slot + w*1024
  // (w>>1 = i-row within pair, w&1 = half). Source advances 4KB per iter.
  const char* qsp = (const char*)(qf + (size_t)(b * 128 + i0base) * 1024)
                    + (w >> 1) * 2048 + (w & 1) * 1024 + lane * 16;

  // ---- LDS read offsets: row-part + swizzled column part.
  // col bytes in [0,128): (kkh*64 + quad*16) ^ ((row&7)<<4); row&7 == l15&7.
  const int swzb = (l15 & 7) << 4;
  const int col0 = (quad * 16) ^ swzb;
  const int col1 = (64 + quad * 16) ^ swzb;
  const int abase = l15 * 128;                       // + mh*8192 + ms*2048
  const int bbase = BG_WE + (wn * 64 + l15) * 128;   // + nh*4096 + ns*2048
  const int qrd = BG_Q + wm * 2048 + quad * 16;      // + (j&1)*4096 + tt*128

  // ---- prologue: q iter0 (oldest loads), then tiles 0 and 1 ----
  if (w < 4) gld16(qsp, lds + BG_Q + w * 1024);
  gld16(ks0, lds + kd0);              gld16(ks1, lds + kd1);
  gld16(ws0, lds + wd0);              gld16(ws1, lds + wd1);
  gld16(ws2, lds + wd2);              gld16(ws3, lds + wd3);
  gld16(ks0 + 128, lds + BG_BUF + kd0); gld16(ks1 + 128, lds + BG_BUF + kd1);
  gld16(ws0 + 128, lds + BG_BUF + wd0); gld16(ws1 + 128, lds + BG_BUF + wd1);
  gld16(ws2 + 128, lds + BG_BUF + wd2); gld16(ws3 + 128, lds + BG_BUF + wd3);

  f32x4 acc[8][4];
  #pragma unroll
  for (int a = 0; a < 8; ++a)
    #pragma unroll
    for (int c = 0; c < 4; ++c) acc[a][c] = (f32x4){0.f, 0.f, 0.f, 0.f};

  f16x8 af[4][2], bf0[2][2], bf1[2][2], qs0, qs1;

#define RD_A(mh)                                                               \
  _Pragma("unroll")                                                            \
  for (int ms = 0; ms < 4; ++ms) {                                             \
    af[ms][0] = *(const f16x8*)(lds + cb + abase + (mh) * 8192 + ms * 2048 + col0); \
    af[ms][1] = *(const f16x8*)(lds + cb + abase + (mh) * 8192 + ms * 2048 + col1); \
  }
#define RD_B(dst, nh)                                                          \
  _Pragma("unroll")                                                            \
  for (int ns = 0; ns < 2; ++ns) {                                             \
    dst[ns][0] = *(const f16x8*)(lds + cb + bbase + (nh) * 4096 + ns * 2048 + col0); \
    dst[ns][1] = *(const f16x8*)(lds + cb + bbase + (nh) * 4096 + ns * 2048 + col1); \
  }
#define MULT_A()                                                               \
  _Pragma("unroll")                                                            \
  for (int ms = 0; ms < 4; ++ms) { af[ms][0] *= qs0; af[ms][1] *= qs1; }
#define MFMA8(MH, NH, BFR)                                                     \
  _Pragma("unroll")                                                            \
  for (int kh = 0; kh < 2; ++kh)                                               \
    _Pragma("unroll")                                                          \
    for (int ms = 0; ms < 4; ++ms)                                             \
      _Pragma("unroll")                                                        \
      for (int ns = 0; ns < 2; ++ns)                                           \
        acc[(MH) * 4 + ms][(NH) * 2 + ns] = __builtin_amdgcn_mfma_f32_16x16x32_f16( \
            af[ms][kh], BFR[ns][kh], acc[(MH) * 4 + ms][(NH) * 2 + ns], 0, 0, 0);
#define BAR() __builtin_amdgcn_s_barrier()
#define LGKM0() asm volatile("s_waitcnt lgkmcnt(0)" ::: "memory")

  int cur = 0;
  #pragma unroll 1
  for (int T = 0; T < 128; ++T) {
    const int cb = cur * BG_BUF;
    int stg = cur + 2; if (stg >= 3) stg -= 3;
    const int sb = stg * BG_BUF;
    const int j = T >> 4, tt = T & 15;
    const int skb = ((T + 2) & 15) * 128;   // global col-byte base of tile T+2
    const bool st = (T < 126);
    // stage q for iter (T+2)>>4 at T in {14,30,...,110}; issued FIRST in
    // this tile's batch so vmcnt(6) accounting stays uniform.
    const bool stq = (w < 4) && (((T + 2) & 15) == 0) && (T + 2 < 128);

    if (T < 127) asm volatile("s_waitcnt vmcnt(6)" ::: "memory");
    else         asm volatile("s_waitcnt vmcnt(0)" ::: "memory");
    BAR();

    // ---- phase 0: (mh0, nh0) ----
    qs0 = *(const f16x8*)(lds + qrd + (j & 1) * 4096 + tt * 128);
    qs1 = *(const f16x8*)(lds + qrd + (j & 1) * 4096 + tt * 128 + 64);
    RD_A(0)
    RD_B(bf0, 0)
    if (stq) gld16(qsp + (T + 2) * 256,
                   lds + BG_Q + ((((T + 2) >> 4) & 1) * 4096) + w * 1024);
    if (st) { gld16(ks0 + skb, lds + sb + kd0); gld16(ks1 + skb, lds + sb + kd1); }
    BAR(); LGKM0();
    __builtin_amdgcn_s_setprio(1);
    MULT_A()
    MFMA8(0, 0, bf0)
    __builtin_amdgcn_s_setprio(0);
    BAR();
    // ---- phase 1: (mh0, nh1) ----
    RD_B(bf1, 1)
    if (st) { gld16(ws0 + skb, lds + sb + wd0); gld16(ws1 + skb, lds + sb + wd1); }
    BAR(); LGKM0();
    __builtin_amdgcn_s_setprio(1);
    MFMA8(0, 1, bf1)
    __builtin_amdgcn_s_setprio(0);
    BAR();
    // ---- phase 2: (mh1, nh1) + (mh1, nh0) — reuse bf1, bf0 ----
    RD_A(1)
    if (st) { gld16(ws2 + skb, lds + sb + wd2); gld16(ws3 + skb, lds + sb + wd3); }
    BAR(); LGKM0();
    __builtin_amdgcn_s_setprio(1);
    MULT_A()
    MFMA8(1, 1, bf1)
    MFMA8(1, 0, bf0)
    __builtin_amdgcn_s_setprio(0);
    BAR();

    cur = cur + 1; if (cur == 3) cur = 0;

    // ---- per-iter epilogue: stores overlap next iter's in-flight prefetch ----
    if (tt == 15) {
      const size_t nb = (size_t)(b * 128 + i0base + 2 * j + wm) * 128;
      const int colb = vtile * 256 + wn * 64;
      #pragma unroll
      for (int ms = 0; ms < 8; ++ms) {
        #pragma unroll
        for (int ns = 0; ns < 4; ++ns) {
          #pragma unroll
          for (int r = 0; r < 4; ++r)
            out[(nb + ms * 16 + quad * 4 + r) * 1024 + colb + ns * 16 + l15] =
                acc[ms][ns][r];
        }
      }
      #pragma unroll
      for (int a = 0; a < 8; ++a)
        #pragma unroll
        for (int c = 0; c < 4; ++c) acc[a][c] = (f32x4){0.f, 0.f, 0.f, 0.f};
    }
  }
#undef RD_A
#undef RD_B
#undef MULT_A
#undef MFMA8
#undef BAR
#undef LGKM0
}

// ------------- mlm_logits: x_h (8192x1024) @ W_mlm^T (32x1024) -------------
// one wave per row; lane: v = lane&31, half-row part = lane>>5.
__global__ __launch_bounds__(256) void mlm_kernel(
    const _Float16* __restrict__ xh, const _Float16* __restrict__ wm,
    float* __restrict__ out) {
  const int w = threadIdx.x >> 6, lane = threadIdx.x & 63;
  const int row = blockIdx.x * 4 + w;
  const int v = lane & 31, part = lane >> 5;
  const f16x8* xr = (const f16x8*)(xh + (size_t)row * 1024 + part * 512);
  const f16x8* wr = (const f16x8*)(wm + (size_t)v * 1024 + part * 512);
  float acc = 0.f;
  #pragma unroll 8
  for (int it = 0; it < 64; ++it) {
    const f16x8 p = xr[it] * wr[it];
    #pragma unroll
    for (int e = 0; e < 8; ++e) acc += (float)p[e];
  }
  acc += __shfl_xor(acc, 32, 64);
  if (part == 0) out[(size_t)row * 32 + v] = acc;
}

// ------- span masks: in_span, mask_aa (out), diag_mask (out), ws copy -------
__global__ __launch_bounds__(256) void span_kernel(
    const int* __restrict__ midx, float* __restrict__ mask_aa,
    float* __restrict__ diag, float* __restrict__ span_ws) {
  __shared__ float flag[1024];
  const int b = blockIdx.x, t = threadIdx.x;
  for (int p = t; p < 1024; p += 256) flag[p] = 0.f;
  __syncthreads();
  if (t < 128) flag[midx[b * 128 + t]] = 1.f;
  __syncthreads();
  for (int p = t; p < 1024; p += 256) {
    const float f = flag[p];
    mask_aa[b * 1024 + p] = f;
    span_ws[b * 1024 + p] = f;
  }
  for (int p = t; p < 16384; p += 256)
    diag[b * 16384 + p] = ((p >> 7) == (p & 127)) ? 1.f : 0.f;
}

// ---------------- pair_mask_aa[b,i,j] = s[b,i]*s[b,j] (8.4M f32) ----------------
__global__ __launch_bounds__(256) void pairmask_kernel(
    const float* __restrict__ span_ws, float* __restrict__ out) {
  const int id = blockIdx.x * 256 + threadIdx.x;  // float4 units, 2M total
  const int b = id >> 18;
  const int rem = id & 262143;
  const int i = rem >> 8;
  const int j4 = rem & 255;
  const float si = span_ws[b * 1024 + i];
  const float4 sj = ((const float4*)(span_ws + b * 1024))[j4];
  float4 o;
  o.x = si * sj.x; o.y = si * sj.y; o.z = si * sj.z; o.w = si * sj.w;
  ((float4*)out)[id] = o;
}

extern "C" void kernel_launch(void* const* d_in, const int* in_sizes, int n_in,
                              void* d_out, int out_size, void* d_ws, size_t ws_size,
                              hipStream_t stream) {
  const float* x_enc = (const float*)d_in[0];
  const float* gam   = (const float*)d_in[1];
  const float* bet   = (const float*)d_in[2];
  const float* Wq    = (const float*)d_in[3];
  const float* Wk    = (const float*)d_in[4];
  const float* We    = (const float*)d_in[5];
  const float* Wm    = (const float*)d_in[6];
  const int*   midx  = (const int*)d_in[7];
  float* out = (float*)d_out;

  char* ws = (char*)d_ws;
  _Float16* x_h  = (_Float16*)(ws);
  _Float16* q_h  = (_Float16*)(ws + ((size_t)16 << 20));
  _Float16* k_h  = (_Float16*)(ws + ((size_t)18 << 20));
  _Float16* wq_h = (_Float16*)(ws + ((size_t)20 << 20));
  _Float16* wk_h = (_Float16*)(ws + ((size_t)22 << 20));
  _Float16* we_h = (_Float16*)(ws + ((size_t)24 << 20));
  _Float16* wm_h = (_Float16*)(ws + ((size_t)26 << 20));
  float* span_ws = (float*)(ws + ((size_t)27 << 20));

  float* o_logits = out;                        // 131072 x 1024
  float* o_mlm    = out + (size_t)134217728;    // 8192 x 32
  float* o_diag   = o_mlm + 262144;             // 131072
  float* o_maskaa = o_diag + 131072;            // 8192
  float* o_pair   = o_maskaa + 8192;            // 8388608

  cvt_kernel<<<3104, 256, 0, stream>>>(Wq, Wk, We, Wm, wq_h, wk_h, we_h, wm_h);
  ln_kernel<<<8192, 256, 0, stream>>>(x_enc, gam, bet, x_h);
  qk_gemm<<<dim3(16, 16, 2), 256, 0, stream>>>(x_h, wq_h, wk_h, midx, q_h, k_h);
  big_gemm<<<dim3(256), 512, 0, stream>>>(q_h, k_h, we_h, o_logits);
  mlm_kernel<<<2048, 256, 0, stream>>>(x_h, wm_h, o_mlm);
  span_kernel<<<8, 256, 0, stream>>>(midx, o_maskaa, o_diag, span_ws);
  pairmask_kernel<<<8192, 256, 0, stream>>>(span_ws, o_pair);
}